// Round 10
// baseline (269.067 us; speedup 1.0000x reference)
//
#include <hip/hip_runtime.h>

#define KS 3
#define OUTC 3
#define FEATC 6
#define PATCH (FEATC * KS * KS)  // 54

#define BDIM 4
#define HDIM 512
#define WDIM 512
#define WQ (WDIM >> 2)            // 128
#define HW ((size_t)HDIM * WDIM)  // 262144

typedef float f32x4 __attribute__((ext_vector_type(4)));

// out[b,o,h,w] = sum_{c,dy,dx} feat[b,c,h+dy-1,w+dx-1] * km[b, o*54 + c*9 + dy*3 + dx, h, w]
//
// One thread: 4 consecutive pixels (w0..w0+3), ALL THREE output channels.
// vs R6 (134.8us, o-split): merge o back into the thread so each feat window
// is fetched once instead of 3x (feat L1/L2 traffic /3, index+store math /3),
// keeping everything R6 proved: nt km loads (R8), 9-load issue-first batches
// (R6), no launch_bounds min-waves (R4/R5 spill trap), scalar boundary loads
// (R9: shuffles regress). Blocks 3072->1024 (R7: block count neutral).
// Register budget: k4[9] fragments (36) + r[3][6] (18) + acc x3 (12) ~ R6-ish.
__global__ __launch_bounds__(256) void supersample_kernel(
    const float* __restrict__ feat,
    const float* __restrict__ km,
    float* __restrict__ out)
{
    const int idx = blockIdx.x * 256 + threadIdx.x;   // 0..262143

    const int wq = idx & (WQ - 1);
    int t = idx >> 7;                 // / WQ
    const int h = t & (HDIM - 1);
    const int b = t >> 9;             // / HDIM
    const int w0 = wq << 2;

    const float* featb = feat + (size_t)b * FEATC * HW;
    const float* kmb   = km   + (size_t)b * OUTC * PATCH * HW
                               + (size_t)h * WDIM + w0;
    float*       outb  = out  + (size_t)b * OUTC * HW + (size_t)h * WDIM + w0;

    f32x4 acc0 = (f32x4)0.f, acc1 = (f32x4)0.f, acc2 = (f32x4)0.f;

#pragma unroll
    for (int c = 0; c < FEATC; ++c) {
        // feat window r[ky][j] = feat[c, h+ky-1, w0-1+j], zero-padded.
        // Loaded ONCE per c, used by all three o's.
        float r[3][6];
#pragma unroll
        for (int ky = 0; ky < 3; ++ky) {
            const int hy = h + ky - 1;
            if (hy < 0 || hy >= HDIM) {
#pragma unroll
                for (int j = 0; j < 6; ++j) r[ky][j] = 0.f;
            } else {
                const float* row = featb + (size_t)c * HW + (size_t)hy * WDIM;
                const f32x4 mid = *reinterpret_cast<const f32x4*>(row + w0);  // aligned
                r[ky][1] = mid.x; r[ky][2] = mid.y; r[ky][3] = mid.z; r[ky][4] = mid.w;
                r[ky][0] = (w0 > 0)        ? row[w0 - 1] : 0.f;
                r[ky][5] = (w0 + 4 < WDIM) ? row[w0 + 4] : 0.f;
            }
        }

        // three 9-load nt km batches, issue-first then FMA, o = 0,1,2
#pragma unroll
        for (int o = 0; o < OUTC; ++o) {
            const float* kmc = kmb + (size_t)((o * PATCH + c * KS * KS)) * HW;
            f32x4 k4[9];
#pragma unroll
            for (int t9 = 0; t9 < 9; ++t9)
                k4[t9] = __builtin_nontemporal_load(
                    reinterpret_cast<const f32x4*>(kmc + (size_t)t9 * HW));

            f32x4 a = (o == 0) ? acc0 : (o == 1) ? acc1 : acc2;
#pragma unroll
            for (int ky = 0; ky < 3; ++ky) {
#pragma unroll
                for (int kx = 0; kx < 3; ++kx) {
                    const f32x4 k = k4[ky * 3 + kx];
                    a.x = fmaf(r[ky][kx + 0], k.x, a.x);
                    a.y = fmaf(r[ky][kx + 1], k.y, a.y);
                    a.z = fmaf(r[ky][kx + 2], k.z, a.z);
                    a.w = fmaf(r[ky][kx + 3], k.w, a.w);
                }
            }
            if (o == 0) acc0 = a; else if (o == 1) acc1 = a; else acc2 = a;
        }
    }

    *reinterpret_cast<f32x4*>(outb + 0 * HW)          = acc0;
    *reinterpret_cast<f32x4*>(outb + 1 * HW)          = acc1;
    *reinterpret_cast<f32x4*>(outb + 2 * (size_t)HW)  = acc2;
}

extern "C" void kernel_launch(void* const* d_in, const int* in_sizes, int n_in,
                              void* d_out, int out_size, void* d_ws, size_t ws_size,
                              hipStream_t stream) {
    const float* feat = (const float*)d_in[0];
    const float* km   = (const float*)d_in[1];
    float* out        = (float*)d_out;

    const int total = BDIM * HDIM * WQ;   // 262144
    const int block = 256;
    const int grid  = total / block;      // 1024, exact
    supersample_kernel<<<grid, block, 0, stream>>>(feat, km, out);
}

// Round 11
// 135.313 us; speedup vs baseline: 1.9885x; 1.9885x over previous
//
#include <hip/hip_runtime.h>

#define KS 3
#define OUTC 3
#define FEATC 6
#define PATCH (FEATC * KS * KS)  // 54

#define BDIM 4
#define HDIM 512
#define WDIM 512
#define WQ (WDIM >> 2)            // 128
#define HW ((size_t)HDIM * WDIM)  // 262144

typedef float f32x4 __attribute__((ext_vector_type(4)));

// out[b,o,h,w] = sum_{c,dy,dx} feat[b,c,h+dy-1,w+dx-1] * km[b, o*54 + c*9 + dy*3 + dx, h, w]
//
// CHAMPION (R6, 134.8us): one thread = 4 consecutive pixels, ONE output
// channel o; 9 nt km loads issued before the feat gather each c-iteration.
// Full A/B ledger on this problem:
//  - o-split across threads        WIN  (277 -> 146, R1->R2)
//  - issue km before feat gather   WIN  (146 -> 134.8, R6)
//  - nt (no-allocate) km loads     WIN  (plain loads 142.8, R8)
//  - km double-buffer (ka/kb)      LOSS (155, R3: +36 VGPR, occupancy drop)
//  - launch_bounds min-waves 6/8   LOSS (481-506, R4/R5: VGPR clamp -> spill)
//  - persistent 1024-block grid    NULL (137, R7)
//  - shuffle boundary loads        LOSS (145, R9: exec-mask fixup cost)
//  - merge 3 o's into one thread   LOSS (269, R10: 3x chain length, 1/3 waves)
// Effective BW 5.4 TB/s on 730 MB vs 6.3-6.9 TB/s linear-copy ceiling: the
// residual is DRAM page-efficiency of 54 concurrent 1MB-strided streams.
__global__ __launch_bounds__(256) void supersample_kernel(
    const float* __restrict__ feat,
    const float* __restrict__ km,
    float* __restrict__ out)
{
    const int idx = blockIdx.x * 256 + threadIdx.x;

    const int wq = idx & (WQ - 1);
    int t = idx >> 7;                 // / WQ
    const int h = t & (HDIM - 1);
    t >>= 9;                          // / HDIM
    const int o = t % OUTC;
    const int b = t / OUTC;
    const int w0 = wq << 2;

    const float* featb = feat + (size_t)b * FEATC * HW;
    const float* kmo   = km   + ((size_t)b * OUTC + o) * PATCH * HW
                               + (size_t)h * WDIM + w0;
    float*       outp  = out  + ((size_t)b * OUTC + o) * HW + (size_t)h * WDIM + w0;

    f32x4 acc = (f32x4)0.f;

#pragma unroll
    for (int c = 0; c < FEATC; ++c) {
        // 1) issue all 9 nt km loads for this (o,c) first — keep HBM queue full
        const float* kmc = kmo + (size_t)(c * KS * KS) * HW;
        f32x4 k4[9];
#pragma unroll
        for (int t9 = 0; t9 < 9; ++t9)
            k4[t9] = __builtin_nontemporal_load(
                reinterpret_cast<const f32x4*>(kmc + (size_t)t9 * HW));

        // 2) feat window r[ky][j] = feat[c, h+ky-1, w0-1+j], zero-padded
        float r[3][6];
#pragma unroll
        for (int ky = 0; ky < 3; ++ky) {
            const int hy = h + ky - 1;
            if (hy < 0 || hy >= HDIM) {
#pragma unroll
                for (int j = 0; j < 6; ++j) r[ky][j] = 0.f;
            } else {
                const float* row = featb + (size_t)c * HW + (size_t)hy * WDIM;
                const f32x4 mid = *reinterpret_cast<const f32x4*>(row + w0);  // aligned
                r[ky][1] = mid.x; r[ky][2] = mid.y; r[ky][3] = mid.z; r[ky][4] = mid.w;
                r[ky][0] = (w0 > 0)        ? row[w0 - 1] : 0.f;
                r[ky][5] = (w0 + 4 < WDIM) ? row[w0 + 4] : 0.f;
            }
        }

        // 3) FMAs
#pragma unroll
        for (int ky = 0; ky < 3; ++ky) {
#pragma unroll
            for (int kx = 0; kx < 3; ++kx) {
                const f32x4 k = k4[ky * 3 + kx];
                acc.x = fmaf(r[ky][kx + 0], k.x, acc.x);
                acc.y = fmaf(r[ky][kx + 1], k.y, acc.y);
                acc.z = fmaf(r[ky][kx + 2], k.z, acc.z);
                acc.w = fmaf(r[ky][kx + 3], k.w, acc.w);
            }
        }
    }

    *reinterpret_cast<f32x4*>(outp) = acc;
}

extern "C" void kernel_launch(void* const* d_in, const int* in_sizes, int n_in,
                              void* d_out, int out_size, void* d_ws, size_t ws_size,
                              hipStream_t stream) {
    const float* feat = (const float*)d_in[0];
    const float* km   = (const float*)d_in[1];
    float* out        = (float*)d_out;

    const int total = BDIM * OUTC * HDIM * WQ;   // 786432
    const int block = 256;
    const int grid  = total / block;             // 3072, exact
    supersample_kernel<<<grid, block, 0, stream>>>(feat, km, out);
}